// Round 1
// baseline (4458.868 us; speedup 1.0000x reference)
//
#include <hip/hip_runtime.h>

// Problem: word_dist[b,v] = sum_k theta[b,k] * softmax_v(alpha[b,k,:] . W[v,:])
// B=128, K=50, L=300, V=50000.  All inputs/outputs f32.
//
// Strategy: fp32-accurate GEMM via fp16 hi/lo split MFMA (3 products), two passes:
//   pass1: per-(b,k,vchunk) partial (max m, sumexp Z) -> stored in d_out scratch region
//   mid  : reduce partials over chunks -> per-row (m_k, theta_k/Z_k) in d_ws
//   pass2: recompute s, out[b,v] = sum_k w_k * exp2((s - m_k)*log2e)

#define B_   128
#define K_   50
#define L_   300
#define V_   50000
#define VT   256        // v columns per block
#define NCH  196        // ceil(V_/VT)
#define NKC  10         // ceil(L_/32)
#define L2E  1.4426950408889634f
#define INV_LOSC (1.0f/2048.0f)

typedef _Float16 half8  __attribute__((ext_vector_type(8)));
typedef _Float16 half4v __attribute__((ext_vector_type(4)));
typedef float    f32x4  __attribute__((ext_vector_type(4)));

// Split f32 -> f16 hi + f16 lo*2048 (lo scaled into normal range; MFMA-subnormal-safe).
__device__ __forceinline__ void split_store(_Float16* ph, _Float16* pl, float4 x) {
  half4v h, l;
  h[0] = (_Float16)x.x; h[1] = (_Float16)x.y; h[2] = (_Float16)x.z; h[3] = (_Float16)x.w;
  l[0] = (_Float16)((x.x - (float)h[0]) * 2048.0f);
  l[1] = (_Float16)((x.y - (float)h[1]) * 2048.0f);
  l[2] = (_Float16)((x.z - (float)h[2]) * 2048.0f);
  l[3] = (_Float16)((x.w - (float)h[3]) * 2048.0f);
  *(half4v*)ph = h;
  *(half4v*)pl = l;
}

// One block: one b (M = 64 rows, 50 real) x VT=256 v columns. 4 waves, each wave owns
// 64 v columns (4 n-tiles), all 4 m-tiles. K-loop: 10 chunks of 32 over L=300.
template<int PASS>
__global__ __launch_bounds__(256, 2)
void detm_gemm(const float* __restrict__ alpha,
               const float* __restrict__ Wm,
               float* __restrict__ out,
               const float* __restrict__ cons)
{
  // 40 f16 row stride (32 data + 8 pad) = 80B: keeps 16B-aligned b128 frag reads,
  // even bank spread (floor 8 word-accesses/bank for wave b128).
  __shared__ _Float16 lAh[64][40];
  __shared__ _Float16 lAl[64][40];
  __shared__ _Float16 lWh[VT][40];
  __shared__ _Float16 lWl[VT][40];
  __shared__ float redM[4][64];   // pass1: per-wave row max | pass2: row m_k (redM[0])
  __shared__ float redZ[4][64];   // pass1: per-wave row sumexp | pass2: row weight (redZ[0])

  const int tid  = threadIdx.x;
  const int bid  = blockIdx.x;
  const int b    = bid & (B_ - 1);
  const int ch   = bid >> 7;
  const int vb   = ch * VT;
  const int wid  = tid >> 6;
  const int lane = tid & 63;
  const int g    = lane >> 4;
  const int c    = lane & 15;

  if (PASS == 2 && tid < 64) {
    redM[0][tid] = cons[(b * 64 + tid) * 2];
    redZ[0][tid] = cons[(b * 64 + tid) * 2 + 1];
  }

  f32x4 accM[4][4] = {};   // hi*hi
  f32x4 accC[4][4] = {};   // hi*lo + lo*hi  (scaled by 2048)

  for (int kc = 0; kc < NKC; ++kc) {
    __syncthreads();
    // ---- stage A tile (64 x 32) with on-the-fly hi/lo split ----
    #pragma unroll
    for (int i = 0; i < 2; ++i) {
      int slot = i * 256 + tid;
      int r = slot >> 3, q = slot & 7;
      int k = kc * 32 + q * 4;
      float4 x = make_float4(0.f, 0.f, 0.f, 0.f);
      if (r < K_ && k < L_) x = *(const float4*)&alpha[((size_t)b * K_ + r) * L_ + k];
      split_store(&lAh[r][q * 4], &lAl[r][q * 4], x);
    }
    // ---- stage W tile (256 x 32) ----
    #pragma unroll
    for (int i = 0; i < 8; ++i) {
      int slot = i * 256 + tid;
      int r = slot >> 3, q = slot & 7;
      int k = kc * 32 + q * 4;
      int v = vb + r;
      float4 x = make_float4(0.f, 0.f, 0.f, 0.f);
      if (v < V_ && k < L_) x = *(const float4*)&Wm[(size_t)v * L_ + k];
      split_store(&lWh[r][q * 4], &lWl[r][q * 4], x);
    }
    __syncthreads();

    // ---- fragments: consistent k-map k=(lane>>4)*8+j for BOTH A and B (k-permutation
    // invariant => exact product regardless of HW's internal k order) ----
    half8 ah[4], al[4];
    #pragma unroll
    for (int mt = 0; mt < 4; ++mt) {
      int row = mt * 16 + c;
      ah[mt] = *(const half8*)&lAh[row][g * 8];
      al[mt] = *(const half8*)&lAl[row][g * 8];
    }
    #pragma unroll
    for (int nt = 0; nt < 4; ++nt) {
      int vrow = wid * 64 + nt * 16 + c;
      half8 bh = *(const half8*)&lWh[vrow][g * 8];
      half8 bl = *(const half8*)&lWl[vrow][g * 8];
      #pragma unroll
      for (int mt = 0; mt < 4; ++mt) {
        accM[mt][nt] = __builtin_amdgcn_mfma_f32_16x16x32_f16(ah[mt], bh, accM[mt][nt], 0, 0, 0);
        accC[mt][nt] = __builtin_amdgcn_mfma_f32_16x16x32_f16(ah[mt], bl, accC[mt][nt], 0, 0, 0);
        accC[mt][nt] = __builtin_amdgcn_mfma_f32_16x16x32_f16(al[mt], bh, accC[mt][nt], 0, 0, 0);
      }
    }
  }

  // s = hi*hi + (cross)/2048   (f32-accurate logits)
  #pragma unroll
  for (int mt = 0; mt < 4; ++mt)
    #pragma unroll
    for (int nt = 0; nt < 4; ++nt)
      accM[mt][nt] = accM[mt][nt] + accC[mt][nt] * INV_LOSC;

  // C layout (verified): col = lane&15, row = (lane>>4)*4 + reg  ->  row = mt*16+g*4+r
  if (PASS == 1) {
    #pragma unroll
    for (int mt = 0; mt < 4; ++mt) {
      #pragma unroll
      for (int r = 0; r < 4; ++r) {
        float m = -INFINITY;
        #pragma unroll
        for (int nt = 0; nt < 4; ++nt) {
          int vcol = vb + wid * 64 + nt * 16 + c;
          if (vcol < V_) m = fmaxf(m, accM[mt][nt][r]);
        }
        m = fmaxf(m, __shfl_xor(m, 1));
        m = fmaxf(m, __shfl_xor(m, 2));
        m = fmaxf(m, __shfl_xor(m, 4));
        m = fmaxf(m, __shfl_xor(m, 8));
        float z = 0.f;
        #pragma unroll
        for (int nt = 0; nt < 4; ++nt) {
          int vcol = vb + wid * 64 + nt * 16 + c;
          if (vcol < V_) z += exp2f((accM[mt][nt][r] - m) * L2E);
        }
        z += __shfl_xor(z, 1);
        z += __shfl_xor(z, 2);
        z += __shfl_xor(z, 4);
        z += __shfl_xor(z, 8);
        if (c == 0) {
          int row = mt * 16 + g * 4 + r;
          redM[wid][row] = m;
          redZ[wid][row] = z;
        }
      }
    }
    __syncthreads();
    if (tid < 64) {
      int row = tid;
      float m0 = redM[0][row], m1 = redM[1][row], m2 = redM[2][row], m3 = redM[3][row];
      float mC = fmaxf(fmaxf(m0, m1), fmaxf(m2, m3));
      float z  = redZ[0][row] * exp2f((m0 - mC) * L2E)
               + redZ[1][row] * exp2f((m1 - mC) * L2E)
               + redZ[2][row] * exp2f((m2 - mC) * L2E)
               + redZ[3][row] * exp2f((m3 - mC) * L2E);
      if (row < K_) {
        size_t idx = ((size_t)b * K_ + row) * NCH + ch;
        out[idx] = mC;                              // partial max
        out[(size_t)B_ * K_ * NCH + idx] = z;       // partial sumexp
      }
    }
  } else {
    // pass2: out[b,v] = sum over the 16 (mt,reg) rows this lane holds, then reduce
    // across the 4 lane-groups (xor 16,32) that hold the other rows of the same column.
    #pragma unroll
    for (int nt = 0; nt < 4; ++nt) {
      int vcol = vb + wid * 64 + nt * 16 + c;
      float t = 0.f;
      #pragma unroll
      for (int mt = 0; mt < 4; ++mt)
        #pragma unroll
        for (int r = 0; r < 4; ++r) {
          int row = mt * 16 + g * 4 + r;
          t += redZ[0][row] * exp2f((accM[mt][nt][r] - redM[0][row]) * L2E);
        }
      t += __shfl_xor(t, 16);
      t += __shfl_xor(t, 32);
      if (g == 0 && vcol < V_) out[(size_t)b * V_ + vcol] = t;
    }
  }
}

// Reduce per-chunk partials -> per-row (m_k, theta_k/Z_k), padded to 64 rows/b.
__global__ void detm_mid(const float* __restrict__ theta,
                         const float* __restrict__ pbuf,
                         float* __restrict__ cons)
{
  int b = blockIdx.x;
  int k = threadIdx.x;        // 0..63
  float m = 0.f, wgt = 0.f;
  if (k < K_) {
    const float* pm = pbuf + ((size_t)b * K_ + k) * NCH;
    const float* pz = pbuf + (size_t)B_ * K_ * NCH + ((size_t)b * K_ + k) * NCH;
    float mx = -INFINITY;
    for (int ch = 0; ch < NCH; ++ch) mx = fmaxf(mx, pm[ch]);
    float z = 0.f;
    for (int ch = 0; ch < NCH; ++ch) z += pz[ch] * exp2f((pm[ch] - mx) * L2E);
    m = mx;
    wgt = theta[b * K_ + k] / z;
  }
  cons[(b * 64 + k) * 2]     = m;
  cons[(b * 64 + k) * 2 + 1] = wgt;
}

extern "C" void kernel_launch(void* const* d_in, const int* in_sizes, int n_in,
                              void* d_out, int out_size, void* d_ws, size_t ws_size,
                              hipStream_t stream) {
  const float* theta = (const float*)d_in[0];
  const float* alpha = (const float*)d_in[1];
  const float* Wm    = (const float*)d_in[2];
  float* out  = (float*)d_out;
  float* cons = (float*)d_ws;   // 128*64*2 f32 = 64 KB

  // pass1: partials (m,Z) into d_out scratch region (fully overwritten by pass2)
  detm_gemm<1><<<dim3(NCH * B_), dim3(256), 0, stream>>>(alpha, Wm, out, cons);
  // reduce partials -> per-row constants in ws
  detm_mid<<<dim3(B_), dim3(64), 0, stream>>>(theta, out, cons);
  // pass2: final output
  detm_gemm<2><<<dim3(NCH * B_), dim3(256), 0, stream>>>(alpha, Wm, out, cons);
}

// Round 2
// 1892.126 us; speedup vs baseline: 2.3565x; 2.3565x over previous
//
#include <hip/hip_runtime.h>

// word_dist[b,v] = sum_k theta[b,k] * softmax_v(alpha[b,k,:] . W[v,:])
// B=128, K=50, L=300, V=50000, f32 in/out.
//
// R2: 2-pass softmax-GEMM. fp16 2-product emulation: s = hiA*hiW + (loA*hiW)/2048
// (W is hi-only f16: dropped hiA*loW term adds ~5e-3 logit noise, ~4e-4 out absmax).
// 4 b's per block (W stage/convert amortized 4x), 8 waves, reg-prefetch of next
// K-chunk overlapping MFMA, single-buffered LDS.

#define B_   128
#define K_   50
#define L_   300
#define V_   50000
#define VT   128
#define NCH  391          // ceil(V_/VT)
#define BG   32           // groups of 4 b's
#define NKC  10           // ceil(L_/32)
#define L2E  1.4426950408889634f
#define LOSC 2048.0f
#define INV_LOSC (1.0f/2048.0f)
#define PART ((size_t)NCH * B_ * K_)   // z-partials offset inside d_out scratch

typedef _Float16 half8  __attribute__((ext_vector_type(8)));
typedef _Float16 half4v __attribute__((ext_vector_type(4)));
typedef float    f32x4  __attribute__((ext_vector_type(4)));

__device__ __forceinline__ void split4(const float4& x, _Float16* ph, _Float16* pl) {
  half4v h, l;
  h[0] = (_Float16)x.x; h[1] = (_Float16)x.y; h[2] = (_Float16)x.z; h[3] = (_Float16)x.w;
  l[0] = (_Float16)((x.x - (float)h[0]) * LOSC);
  l[1] = (_Float16)((x.y - (float)h[1]) * LOSC);
  l[2] = (_Float16)((x.z - (float)h[2]) * LOSC);
  l[3] = (_Float16)((x.w - (float)h[3]) * LOSC);
  *(half4v*)ph = h;
  *(half4v*)pl = l;
}

__device__ __forceinline__ void cvt4(const float4& x, _Float16* ph) {
  half4v h;
  h[0] = (_Float16)x.x; h[1] = (_Float16)x.y; h[2] = (_Float16)x.z; h[3] = (_Float16)x.w;
  *(half4v*)ph = h;
}

// Block: 4 b's (rows padded to 64 each -> 256 A rows) x VT=128 v cols. 8 waves:
// wave = (b-slot, col-half). Per wave: 4 m-tiles x 4 n-tiles, 2 MFMA each.
template<int PASS>
__global__ __launch_bounds__(512, 2)
void detm_gemm(const float* __restrict__ alpha,
               const float* __restrict__ Wm,
               float* __restrict__ out,
               const float* __restrict__ cons)
{
  // stride 40 f16 = 80B: 16B-aligned b128 frag reads, worst 2-way read conflict.
  __shared__ _Float16 lAh[256][40];
  __shared__ _Float16 lAl[256][40];
  __shared__ _Float16 lWh[128][40];
  __shared__ float redM[8][64];
  __shared__ float redZ[8][64];

  const int tid  = threadIdx.x;
  const int bid  = blockIdx.x;
  const int ch   = bid / BG;       // 32 consecutive blocks share a W chunk (L2 reuse)
  const int bg   = bid % BG;
  const int vb   = ch * VT;
  const int wid  = tid >> 6;
  const int lane = tid & 63;
  const int g    = lane >> 4;
  const int c    = lane & 15;
  const int slot = wid >> 1;       // b-slot 0..3
  const int half = wid & 1;        // col half 0..1

  if (PASS == 2 && tid < 256) {    // per-row m_k and theta_k/Z_k (redM/redZ reused)
    int s = tid >> 6, row = tid & 63;
    int b = bg * 4 + s;
    ((float*)redM)[tid] = cons[(b * 64 + row) * 2];
    ((float*)redZ)[tid] = cons[(b * 64 + row) * 2 + 1];
  }

  float4 pf[6];
  auto issue = [&](int kc) {
    #pragma unroll
    for (int i = 0; i < 4; ++i) {            // A: 256 rows x 8 quads
      int idx = i * 512 + tid;
      int arow = idx >> 3, q = idx & 7;
      int bslot = arow >> 6, brow = arow & 63;
      int col = kc * 32 + q * 4;
      float4 x = make_float4(0.f, 0.f, 0.f, 0.f);
      if (brow < K_ && col < L_)
        x = *(const float4*)&alpha[(((size_t)(bg * 4 + bslot)) * K_ + brow) * L_ + col];
      pf[i] = x;
    }
    #pragma unroll
    for (int i = 0; i < 2; ++i) {            // W: 128 rows x 8 quads
      int idx = i * 512 + tid;
      int wrow = idx >> 3, q = idx & 7;
      int col = kc * 32 + q * 4;
      int v = vb + wrow;
      float4 x = make_float4(0.f, 0.f, 0.f, 0.f);
      if (v < V_ && col < L_)
        x = *(const float4*)&Wm[(size_t)v * L_ + col];
      pf[4 + i] = x;
    }
  };

  f32x4 accM[4][4] = {};   // hiA*hiW
  f32x4 accC[4][4] = {};   // loA*hiW (x2048)

  issue(0);
  for (int kc = 0; kc < NKC; ++kc) {
    if (kc) __syncthreads();                 // all reads of previous tile done
    #pragma unroll
    for (int i = 0; i < 4; ++i) {
      int idx = i * 512 + tid;
      int arow = idx >> 3, q = idx & 7;
      split4(pf[i], &lAh[arow][q * 4], &lAl[arow][q * 4]);
    }
    #pragma unroll
    for (int i = 0; i < 2; ++i) {
      int idx = i * 512 + tid;
      int wrow = idx >> 3, q = idx & 7;
      cvt4(pf[4 + i], &lWh[wrow][q * 4]);
    }
    __syncthreads();                         // tile ready
    if (kc + 1 < NKC) issue(kc + 1);         // prefetch overlaps MFMA below

    half8 ah[4], al[4];
    #pragma unroll
    for (int mt = 0; mt < 4; ++mt) {
      int row = slot * 64 + mt * 16 + c;
      ah[mt] = *(const half8*)&lAh[row][g * 8];
      al[mt] = *(const half8*)&lAl[row][g * 8];
    }
    #pragma unroll
    for (int nt = 0; nt < 4; ++nt) {
      int wrow = half * 64 + nt * 16 + c;
      half8 bh = *(const half8*)&lWh[wrow][g * 8];
      #pragma unroll
      for (int mt = 0; mt < 4; ++mt) {
        accM[mt][nt] = __builtin_amdgcn_mfma_f32_16x16x32_f16(ah[mt], bh, accM[mt][nt], 0, 0, 0);
        accC[mt][nt] = __builtin_amdgcn_mfma_f32_16x16x32_f16(al[mt], bh, accC[mt][nt], 0, 0, 0);
      }
    }
  }

  #pragma unroll
  for (int mt = 0; mt < 4; ++mt)
    #pragma unroll
    for (int nt = 0; nt < 4; ++nt)
      accM[mt][nt] = accM[mt][nt] + accC[mt][nt] * INV_LOSC;

  // C layout: col = lane&15 (c), row = mt*16 + g*4 + reg
  if (PASS == 1) {
    #pragma unroll
    for (int mt = 0; mt < 4; ++mt) {
      #pragma unroll
      for (int r = 0; r < 4; ++r) {
        float m = -INFINITY;
        #pragma unroll
        for (int nt = 0; nt < 4; ++nt) {
          int vcol = vb + half * 64 + nt * 16 + c;
          if (vcol < V_) m = fmaxf(m, accM[mt][nt][r]);
        }
        m = fmaxf(m, __shfl_xor(m, 1));
        m = fmaxf(m, __shfl_xor(m, 2));
        m = fmaxf(m, __shfl_xor(m, 4));
        m = fmaxf(m, __shfl_xor(m, 8));
        float z = 0.f;
        #pragma unroll
        for (int nt = 0; nt < 4; ++nt) {
          int vcol = vb + half * 64 + nt * 16 + c;
          if (vcol < V_) z += exp2f((accM[mt][nt][r] - m) * L2E);
        }
        z += __shfl_xor(z, 1);
        z += __shfl_xor(z, 2);
        z += __shfl_xor(z, 4);
        z += __shfl_xor(z, 8);
        if (c == 0) {
          int row = mt * 16 + g * 4 + r;
          redM[wid][row] = m;
          redZ[wid][row] = z;
        }
      }
    }
    __syncthreads();
    if (tid < 256) {                         // combine the 2 col-half waves per b-slot
      int s = tid >> 6, row = tid & 63;
      float m0 = redM[s * 2][row],  m1 = redM[s * 2 + 1][row];
      float z0 = redZ[s * 2][row],  z1 = redZ[s * 2 + 1][row];
      float m = fmaxf(m0, m1);
      float z = z0 * exp2f((m0 - m) * L2E) + z1 * exp2f((m1 - m) * L2E);
      if (row < K_) {
        int b = bg * 4 + s;
        size_t idx = ((size_t)ch * B_ + b) * K_ + row;   // [ch][b][k]: coalesced for mid
        out[idx] = m;
        out[PART + idx] = z;
      }
    }
  } else {
    const float* sM = (const float*)redM;
    const float* sW = (const float*)redZ;
    #pragma unroll
    for (int nt = 0; nt < 4; ++nt) {
      int vcol = vb + half * 64 + nt * 16 + c;
      float t = 0.f;
      #pragma unroll
      for (int mt = 0; mt < 4; ++mt)
        #pragma unroll
        for (int r = 0; r < 4; ++r) {
          int row = slot * 64 + mt * 16 + g * 4 + r;
          t += sW[row] * exp2f((accM[mt][nt][r] - sM[row]) * L2E);
        }
      t += __shfl_xor(t, 16);
      t += __shfl_xor(t, 32);
      if (g == 0 && vcol < V_)
        out[(size_t)(bg * 4 + slot) * V_ + vcol] = t;
    }
  }
}

// Reduce per-chunk partials -> per-row (m_k, theta_k/Z_k). 4 segments scan
// NCH/4 chunks each (coalesced over k), then combine.
__global__ void detm_mid(const float* __restrict__ theta,
                         const float* __restrict__ pbuf,
                         float* __restrict__ cons)
{
  __shared__ float sm[4][64], sz[4][64];
  int b = blockIdx.x, t = threadIdx.x;
  int k = t & 63, seg = t >> 6;
  float mx = -INFINITY, z = 0.f;
  if (k < K_) {
    for (int ch = seg; ch < NCH; ch += 4) {
      size_t idx = ((size_t)ch * B_ + b) * K_ + k;
      float m = pbuf[idx];
      float zz = pbuf[PART + idx];
      float nm = fmaxf(mx, m);
      z = z * exp2f((mx - nm) * L2E) + zz * exp2f((m - nm) * L2E);
      mx = nm;
    }
  }
  sm[seg][k] = mx; sz[seg][k] = z;
  __syncthreads();
  if (seg == 0) {
    float m = sm[0][k];
    #pragma unroll
    for (int s = 1; s < 4; ++s) m = fmaxf(m, sm[s][k]);
    float zt = 0.f;
    #pragma unroll
    for (int s = 0; s < 4; ++s) zt += sz[s][k] * exp2f((sm[s][k] - m) * L2E);
    float mm = 0.f, wgt = 0.f;
    if (k < K_) { mm = m; wgt = theta[b * K_ + k] / zt; }
    cons[(b * 64 + k) * 2]     = mm;
    cons[(b * 64 + k) * 2 + 1] = wgt;
  }
}

extern "C" void kernel_launch(void* const* d_in, const int* in_sizes, int n_in,
                              void* d_out, int out_size, void* d_ws, size_t ws_size,
                              hipStream_t stream) {
  const float* theta = (const float*)d_in[0];
  const float* alpha = (const float*)d_in[1];
  const float* Wm    = (const float*)d_in[2];
  float* out  = (float*)d_out;
  float* cons = (float*)d_ws;   // 128*64*2 f32 = 64 KB

  detm_gemm<1><<<dim3(NCH * BG), dim3(512), 0, stream>>>(alpha, Wm, out, cons);
  detm_mid<<<dim3(B_), dim3(256), 0, stream>>>(theta, out, cons);
  detm_gemm<2><<<dim3(NCH * BG), dim3(512), 0, stream>>>(alpha, Wm, out, cons);
}

// Round 12
// 1434.948 us; speedup vs baseline: 3.1073x; 1.3186x over previous
//
#include <hip/hip_runtime.h>

// word_dist[b,v] = sum_k theta[b,k] * softmax_v(alpha[b,k,:] . W[v,:])
// B=128, K=50, L=300, V=50000, f32 in/out.
//
// R3 resubmit #9 (R3/R10: container failed; R4-R9, R11: acquisition timeouts).
// Audit: no OOB, no divergent barriers, graph-capture-safe, re-poison-safe.
// Precompute f16 hi/lo fragments of A and f16-hi fragments of W into d_ws
// (fragment layout = exactly the order MFMA lanes consume), then a barrier-free,
// LDS-free 2-pass softmax-GEMM: per kc just 12 global b128 loads (L2/L3-hot,
// ping-pong double-buffered) + 32 MFMA per wave. s = hiA*hiW + (loA*hiW)/2048.
// Falls back to the R2 kernel when ws_size is too small for the fragment buffers.

#define B_   128
#define K_   50
#define L_   300
#define V_   50000
#define VT   128
#define NCH  391          // ceil(V_/VT)
#define BG   32           // legacy: groups of 4 b's
#define NKC  10           // ceil(L_/32)
#define L2E  1.4426950408889634f
#define LOSC 2048.0f
#define INV_LOSC (1.0f/2048.0f)
#define PART ((size_t)NCH * B_ * K_)   // z-partials offset inside d_out scratch

#define AFR_ENT ((size_t)B_ * NKC * 4 * 64)      // 327,680 half8 entries
#define WFR_ENT ((size_t)NCH * NKC * 4 * 128)    // 2,001,920 half8 entries
#define A_BYTES (AFR_ENT * 16)
#define W_BYTES (WFR_ENT * 16)
#define WS_NEED (2 * A_BYTES + W_BYTES + 65536)

typedef _Float16 half8  __attribute__((ext_vector_type(8)));
typedef _Float16 half4v __attribute__((ext_vector_type(4)));
typedef float    f32x4  __attribute__((ext_vector_type(4)));

__device__ __forceinline__ void split4(const float4& x, _Float16* ph, _Float16* pl) {
  half4v h, l;
  h[0] = (_Float16)x.x; h[1] = (_Float16)x.y; h[2] = (_Float16)x.z; h[3] = (_Float16)x.w;
  l[0] = (_Float16)((x.x - (float)h[0]) * LOSC);
  l[1] = (_Float16)((x.y - (float)h[1]) * LOSC);
  l[2] = (_Float16)((x.z - (float)h[2]) * LOSC);
  l[3] = (_Float16)((x.w - (float)h[3]) * LOSC);
  *(half4v*)ph = h;
  *(half4v*)pl = l;
}

__device__ __forceinline__ void cvt4(const float4& x, _Float16* ph) {
  half4v h;
  h[0] = (_Float16)x.x; h[1] = (_Float16)x.y; h[2] = (_Float16)x.z; h[3] = (_Float16)x.w;
  *(half4v*)ph = h;
}

// ---------------- precompute: A -> hi/lo fragments ----------------
// Entry t: row(k-topic)=t&63, g=(t>>6)&3, (b*10+kc)=t>>8.
// Ah[t][j] = f16(alpha[b][row][kc*32+g*8+j]), Al = scaled residual.
__global__ void pre_a(const float* __restrict__ alpha,
                      half8* __restrict__ Ah, half8* __restrict__ Al)
{
  int t = blockIdx.x * 256 + threadIdx.x;     // < AFR_ENT
  int row = t & 63;
  int g   = (t >> 6) & 3;
  int q   = t >> 8;
  int kc  = q % NKC, b = q / NKC;
  half8 h = {}, l = {};
  if (row < K_) {
    int l0 = kc * 32 + g * 8;
    #pragma unroll
    for (int j = 0; j < 8; ++j) {
      int lc = l0 + j;
      float x = (lc < L_) ? alpha[((size_t)b * K_ + row) * L_ + lc] : 0.f;
      _Float16 hh = (_Float16)x;
      h[j] = hh;
      l[j] = (_Float16)((x - (float)hh) * LOSC);
    }
  }
  Ah[t] = h; Al[t] = l;
}

// ---------------- precompute: W -> f16 fragments (LDS-staged, coalesced) ------
__global__ __launch_bounds__(256)
void pre_w(const float* __restrict__ Wm, half8* __restrict__ Wh)
{
  __shared__ float sP[32][304];
  int t = threadIdx.x;
  int v0 = blockIdx.x * 32;                   // panel of 32 v's, within one ch
  #pragma unroll
  for (int i = 0; i < 10; ++i) {
    int idx = i * 256 + t;
    if (idx < 2400) {                          // 32 rows x 75 float4
      int r = idx / 75, qd = idx % 75;
      int v = v0 + r;
      float4 x = make_float4(0.f, 0.f, 0.f, 0.f);
      if (v < V_) x = *(const float4*)&Wm[(size_t)v * L_ + qd * 4];
      *(float4*)&sP[r][qd * 4] = x;
    }
  }
  if (t < 128) sP[t >> 2][300 + (t & 3)] = 0.f;   // pad cols 300..303
  __syncthreads();
  int ch = v0 >> 7, r0 = v0 & 127;
  #pragma unroll
  for (int i = 0; i < 5; ++i) {
    int e = i * 256 + t;                       // < 1280
    int row = e & 31, g = (e >> 5) & 3, kc = e >> 7;
    int l0 = kc * 32 + g * 8;
    half8 h = {};
    if (l0 <= 296) {
      #pragma unroll
      for (int j = 0; j < 8; ++j) h[j] = (_Float16)sP[row][l0 + j];
    }
    Wh[(((size_t)ch * NKC + kc) * 4 + g) * 128 + r0 + row] = h;
  }
}

// ---------------- fast GEMM: no LDS staging, no loop barriers ----------------
// Block: 256 thr = 4 waves = (b-slot 0..1) x (col-half 0..1); 2 b's x VT=128 cols.
// Per wave: 4 m-tiles x 4 n-tiles, 2 MFMA each (hi + lo-cross).
template<int PASS>
__global__ __launch_bounds__(256, 2)
void detm_gemm_fast(const half8* __restrict__ Ah, const half8* __restrict__ Al,
                    const half8* __restrict__ Wh, float* __restrict__ out,
                    const float* __restrict__ cons)
{
  __shared__ float redM[4][64];
  __shared__ float redZ[4][64];
  __shared__ float sM[128], sW[128];

  const int tid  = threadIdx.x;
  const int bid  = blockIdx.x;
  const int ch   = bid >> 6;        // 64 consecutive blocks share a W chunk
  const int bg   = bid & 63;
  const int vb   = ch * VT;
  const int wid  = tid >> 6;
  const int lane = tid & 63;
  const int slot = wid >> 1;
  const int hf   = wid & 1;
  const int g    = lane >> 4;
  const int c    = lane & 15;
  const int b    = bg * 2 + slot;

  if (PASS == 2) {
    if (tid < 128) {
      int s = tid >> 6, row = tid & 63;
      sM[tid] = cons[((bg * 2 + s) * 64 + row) * 2];
      sW[tid] = cons[((bg * 2 + s) * 64 + row) * 2 + 1];
    }
    __syncthreads();
  }

  // fragment bases (half8 units): aoff = b*2560 + kc*256 + g*64 + mt*16 + c
  //                               woff = ch*5120 + kc*512 + g*128 + hf*64 + nt*16 + c
  const half8* Abase = Ah + (size_t)b * (NKC * 256) + g * 64 + c;
  const half8* Lbase = Al + (size_t)b * (NKC * 256) + g * 64 + c;
  const half8* Wbase = Wh + (size_t)ch * (NKC * 512) + g * 128 + hf * 64 + c;

  f32x4 accM[4][4] = {};   // hiA*hiW
  f32x4 accC[4][4] = {};   // loA*hiW (x2048)
  half8 a0[4], e0[4], w0[4], a1[4], e1[4], w1[4];

  auto LOADK = [&](int kc, half8* A_, half8* E_, half8* W_) {
    #pragma unroll
    for (int mt = 0; mt < 4; ++mt) {
      A_[mt] = Abase[kc * 256 + mt * 16];
      E_[mt] = Lbase[kc * 256 + mt * 16];
    }
    #pragma unroll
    for (int nt = 0; nt < 4; ++nt)
      W_[nt] = Wbase[kc * 512 + nt * 16];
  };
  auto MF = [&](half8* A_, half8* E_, half8* W_) {
    #pragma unroll
    for (int nt = 0; nt < 4; ++nt)
      #pragma unroll
      for (int mt = 0; mt < 4; ++mt) {
        accM[mt][nt] = __builtin_amdgcn_mfma_f32_16x16x32_f16(A_[mt], W_[nt], accM[mt][nt], 0, 0, 0);
        accC[mt][nt] = __builtin_amdgcn_mfma_f32_16x16x32_f16(E_[mt], W_[nt], accC[mt][nt], 0, 0, 0);
      }
  };

  LOADK(0, a0, e0, w0);
  #pragma unroll
  for (int kc = 0; kc < NKC; kc += 2) {
    LOADK(kc + 1, a1, e1, w1);
    MF(a0, e0, w0);
    if (kc + 2 < NKC) LOADK(kc + 2, a0, e0, w0);
    MF(a1, e1, w1);
  }

  #pragma unroll
  for (int mt = 0; mt < 4; ++mt)
    #pragma unroll
    for (int nt = 0; nt < 4; ++nt)
      accM[mt][nt] = accM[mt][nt] + accC[mt][nt] * INV_LOSC;

  // C layout: col = c, row = mt*16 + g*4 + reg
  if (PASS == 1) {
    #pragma unroll
    for (int mt = 0; mt < 4; ++mt) {
      #pragma unroll
      for (int r = 0; r < 4; ++r) {
        float m = -INFINITY;
        #pragma unroll
        for (int nt = 0; nt < 4; ++nt) {
          int vcol = vb + hf * 64 + nt * 16 + c;
          if (vcol < V_) m = fmaxf(m, accM[mt][nt][r]);
        }
        m = fmaxf(m, __shfl_xor(m, 1));
        m = fmaxf(m, __shfl_xor(m, 2));
        m = fmaxf(m, __shfl_xor(m, 4));
        m = fmaxf(m, __shfl_xor(m, 8));
        float z = 0.f;
        #pragma unroll
        for (int nt = 0; nt < 4; ++nt) {
          int vcol = vb + hf * 64 + nt * 16 + c;
          if (vcol < V_) z += exp2f((accM[mt][nt][r] - m) * L2E);
        }
        z += __shfl_xor(z, 1);
        z += __shfl_xor(z, 2);
        z += __shfl_xor(z, 4);
        z += __shfl_xor(z, 8);
        if (c == 0) {
          int row = mt * 16 + g * 4 + r;
          redM[wid][row] = m;
          redZ[wid][row] = z;
        }
      }
    }
    __syncthreads();
    if (tid < 128) {                 // combine the 2 col-half waves per b-slot
      int s = tid >> 6, row = tid & 63;
      float m0 = redM[s * 2][row], m1 = redM[s * 2 + 1][row];
      float z0 = redZ[s * 2][row], z1 = redZ[s * 2 + 1][row];
      float m = fmaxf(m0, m1);
      float z = z0 * exp2f((m0 - m) * L2E) + z1 * exp2f((m1 - m) * L2E);
      if (row < K_) {
        size_t idx = ((size_t)ch * B_ + (bg * 2 + s)) * K_ + row;
        out[idx] = m;
        out[PART + idx] = z;
      }
    }
  } else {
    #pragma unroll
    for (int nt = 0; nt < 4; ++nt) {
      int vcol = vb + hf * 64 + nt * 16 + c;
      float t = 0.f;
      #pragma unroll
      for (int mt = 0; mt < 4; ++mt)
        #pragma unroll
        for (int r = 0; r < 4; ++r) {
          int row = slot * 64 + mt * 16 + g * 4 + r;
          t += sW[row] * exp2f((accM[mt][nt][r] - sM[row]) * L2E);
        }
      t += __shfl_xor(t, 16);
      t += __shfl_xor(t, 32);
      if (g == 0 && vcol < V_)
        out[(size_t)b * V_ + vcol] = t;
    }
  }
}

// ---------------- legacy (R2) kernel: used when ws_size < WS_NEED -------------
template<int PASS>
__global__ __launch_bounds__(512, 2)
void detm_gemm_legacy(const float* __restrict__ alpha,
                      const float* __restrict__ Wm,
                      float* __restrict__ out,
                      const float* __restrict__ cons)
{
  __shared__ _Float16 lAh[256][40];
  __shared__ _Float16 lAl[256][40];
  __shared__ _Float16 lWh[128][40];
  __shared__ float redM[8][64];
  __shared__ float redZ[8][64];

  const int tid  = threadIdx.x;
  const int bid  = blockIdx.x;
  const int ch   = bid / BG;
  const int bg   = bid % BG;
  const int vb   = ch * VT;
  const int wid  = tid >> 6;
  const int lane = tid & 63;
  const int g    = lane >> 4;
  const int c    = lane & 15;
  const int slot = wid >> 1;
  const int hf   = wid & 1;

  if (PASS == 2 && tid < 256) {
    int s = tid >> 6, row = tid & 63;
    int b = bg * 4 + s;
    ((float*)redM)[tid] = cons[(b * 64 + row) * 2];
    ((float*)redZ)[tid] = cons[(b * 64 + row) * 2 + 1];
  }

  float4 pf[6];
  auto issue = [&](int kc) {
    #pragma unroll
    for (int i = 0; i < 4; ++i) {
      int idx = i * 512 + tid;
      int arow = idx >> 3, q = idx & 7;
      int bslot = arow >> 6, brow = arow & 63;
      int col = kc * 32 + q * 4;
      float4 x = make_float4(0.f, 0.f, 0.f, 0.f);
      if (brow < K_ && col < L_)
        x = *(const float4*)&alpha[(((size_t)(bg * 4 + bslot)) * K_ + brow) * L_ + col];
      pf[i] = x;
    }
    #pragma unroll
    for (int i = 0; i < 2; ++i) {
      int idx = i * 512 + tid;
      int wrow = idx >> 3, q = idx & 7;
      int col = kc * 32 + q * 4;
      int v = vb + wrow;
      float4 x = make_float4(0.f, 0.f, 0.f, 0.f);
      if (v < V_ && col < L_)
        x = *(const float4*)&Wm[(size_t)v * L_ + col];
      pf[4 + i] = x;
    }
  };

  f32x4 accM[4][4] = {};
  f32x4 accC[4][4] = {};

  issue(0);
  for (int kc = 0; kc < NKC; ++kc) {
    if (kc) __syncthreads();
    #pragma unroll
    for (int i = 0; i < 4; ++i) {
      int idx = i * 512 + tid;
      int arow = idx >> 3, q = idx & 7;
      split4(pf[i], &lAh[arow][q * 4], &lAl[arow][q * 4]);
    }
    #pragma unroll
    for (int i = 0; i < 2; ++i) {
      int idx = i * 512 + tid;
      int wrow = idx >> 3, q = idx & 7;
      cvt4(pf[4 + i], &lWh[wrow][q * 4]);
    }
    __syncthreads();
    if (kc + 1 < NKC) issue(kc + 1);

    half8 ah[4], al[4];
    #pragma unroll
    for (int mt = 0; mt < 4; ++mt) {
      int row = slot * 64 + mt * 16 + c;
      ah[mt] = *(const half8*)&lAh[row][g * 8];
      al[mt] = *(const half8*)&lAl[row][g * 8];
    }
    #pragma unroll
    for (int nt = 0; nt < 4; ++nt) {
      int wrow = hf * 64 + nt * 16 + c;
      half8 bh = *(const half8*)&lWh[wrow][g * 8];
      #pragma unroll
      for (int mt = 0; mt < 4; ++mt) {
        accM[mt][nt] = __builtin_amdgcn_mfma_f32_16x16x32_f16(ah[mt], bh, accM[mt][nt], 0, 0, 0);
        accC[mt][nt] = __builtin_amdgcn_mfma_f32_16x16x32_f16(al[mt], bh, accC[mt][nt], 0, 0, 0);
      }
    }
  }

  #pragma unroll
  for (int mt = 0; mt < 4; ++mt)
    #pragma unroll
    for (int nt = 0; nt < 4; ++nt)
      accM[mt][nt] = accM[mt][nt] + accC[mt][nt] * INV_LOSC;

  if (PASS == 1) {
    #pragma unroll
    for (int mt = 0; mt < 4; ++mt) {
      #pragma unroll
      for (int r = 0; r < 4; ++r) {
        float m = -INFINITY;
        #pragma unroll
        for (int nt = 0; nt < 4; ++nt) {
          int vcol = vb + hf * 64 + nt * 16 + c;
          if (vcol < V_) m = fmaxf(m, accM[mt][nt][r]);
        }
        m = fmaxf(m, __shfl_xor(m, 1));
        m = fmaxf(m, __shfl_xor(m, 2));
        m = fmaxf(m, __shfl_xor(m, 4));
        m = fmaxf(m, __shfl_xor(m, 8));
        float z = 0.f;
        #pragma unroll
        for (int nt = 0; nt < 4; ++nt) {
          int vcol = vb + hf * 64 + nt * 16 + c;
          if (vcol < V_) z += exp2f((accM[mt][nt][r] - m) * L2E);
        }
        z += __shfl_xor(z, 1);
        z += __shfl_xor(z, 2);
        z += __shfl_xor(z, 4);
        z += __shfl_xor(z, 8);
        if (c == 0) {
          int row = mt * 16 + g * 4 + r;
          redM[wid][row] = m;
          redZ[wid][row] = z;
        }
      }
    }
    __syncthreads();
    if (tid < 256) {
      int s = tid >> 6, row = tid & 63;
      float m0 = redM[s * 2][row],  m1 = redM[s * 2 + 1][row];
      float z0 = redZ[s * 2][row],  z1 = redZ[s * 2 + 1][row];
      float m = fmaxf(m0, m1);
      float z = z0 * exp2f((m0 - m) * L2E) + z1 * exp2f((m1 - m) * L2E);
      if (row < K_) {
        int b = bg * 4 + s;
        size_t idx = ((size_t)ch * B_ + b) * K_ + row;
        out[idx] = m;
        out[PART + idx] = z;
      }
    }
  } else {
    const float* sM = (const float*)redM;
    const float* sW = (const float*)redZ;
    #pragma unroll
    for (int nt = 0; nt < 4; ++nt) {
      int vcol = vb + hf * 64 + nt * 16 + c;
      float t = 0.f;
      #pragma unroll
      for (int mt = 0; mt < 4; ++mt)
        #pragma unroll
        for (int r = 0; r < 4; ++r) {
          int row = slot * 64 + mt * 16 + g * 4 + r;
          t += sW[row] * exp2f((accM[mt][nt][r] - sM[row]) * L2E);
        }
      t += __shfl_xor(t, 16);
      t += __shfl_xor(t, 32);
      if (g == 0 && vcol < V_)
        out[(size_t)(bg * 4 + slot) * V_ + vcol] = t;
    }
  }
}

// Reduce per-chunk partials -> per-row (m_k, theta_k/Z_k).
__global__ void detm_mid(const float* __restrict__ theta,
                         const float* __restrict__ pbuf,
                         float* __restrict__ cons)
{
  __shared__ float sm[4][64], sz[4][64];
  int b = blockIdx.x, t = threadIdx.x;
  int k = t & 63, seg = t >> 6;
  float mx = -INFINITY, z = 0.f;
  if (k < K_) {
    for (int ch = seg; ch < NCH; ch += 4) {
      size_t idx = ((size_t)ch * B_ + b) * K_ + k;
      float m = pbuf[idx];
      float zz = pbuf[PART + idx];
      float nm = fmaxf(mx, m);
      z = z * exp2f((mx - nm) * L2E) + zz * exp2f((m - nm) * L2E);
      mx = nm;
    }
  }
  sm[seg][k] = mx; sz[seg][k] = z;
  __syncthreads();
  if (seg == 0) {
    float m = sm[0][k];
    #pragma unroll
    for (int s = 1; s < 4; ++s) m = fmaxf(m, sm[s][k]);
    float zt = 0.f;
    #pragma unroll
    for (int s = 0; s < 4; ++s) zt += sz[s][k] * exp2f((sm[s][k] - m) * L2E);
    float mm = 0.f, wgt = 0.f;
    if (k < K_) { mm = m; wgt = theta[b * K_ + k] / zt; }
    cons[(b * 64 + k) * 2]     = mm;
    cons[(b * 64 + k) * 2 + 1] = wgt;
  }
}

extern "C" void kernel_launch(void* const* d_in, const int* in_sizes, int n_in,
                              void* d_out, int out_size, void* d_ws, size_t ws_size,
                              hipStream_t stream) {
  const float* theta = (const float*)d_in[0];
  const float* alpha = (const float*)d_in[1];
  const float* Wm    = (const float*)d_in[2];
  float* out = (float*)d_out;

  if (ws_size >= WS_NEED) {
    half8* Ah = (half8*)d_ws;
    half8* Al = Ah + AFR_ENT;
    half8* Wh = Al + AFR_ENT;
    float* cons = (float*)((char*)d_ws + 2 * A_BYTES + W_BYTES);

    pre_a<<<dim3((int)(AFR_ENT / 256)), dim3(256), 0, stream>>>(alpha, Ah, Al);
    pre_w<<<dim3((V_ + 47 + 32 - 1) / 32), dim3(256), 0, stream>>>(Wm, Wh);  // 1564 panels
    detm_gemm_fast<1><<<dim3(NCH * 64), dim3(256), 0, stream>>>(Ah, Al, Wh, out, cons);
    detm_mid<<<dim3(B_), dim3(256), 0, stream>>>(theta, out, cons);
    detm_gemm_fast<2><<<dim3(NCH * 64), dim3(256), 0, stream>>>(Ah, Al, Wh, out, cons);
  } else {
    float* cons = (float*)d_ws;   // 64 KB
    detm_gemm_legacy<1><<<dim3(NCH * BG), dim3(512), 0, stream>>>(alpha, Wm, out, cons);
    detm_mid<<<dim3(B_), dim3(256), 0, stream>>>(theta, out, cons);
    detm_gemm_legacy<2><<<dim3(NCH * BG), dim3(512), 0, stream>>>(alpha, Wm, out, cons);
  }
}

// Round 13
// 1129.446 us; speedup vs baseline: 3.9478x; 1.2705x over previous
//
#include <hip/hip_runtime.h>

// word_dist[b,v] = sum_k theta[b,k] * softmax_v(alpha[b,k,:] . W[v,:])
// B=128, K=50, L=300, V=50000, f32 in/out.
//
// R13: R3 structure (precomputed MFMA-layout f16 fragments, barrier-free
// LDS-free GEMM loop) + pass1 is now HI-ONLY (drops the loA*hiW product):
// m-error cancels exactly in the output; Z noise ~5e-3 relative worst-case.
// Pass2 keeps the 2-product emulation (s = hiA*hiW + (loA*hiW)/2048).
// Falls back to the R2 kernel when ws_size is too small for fragment buffers.

#define B_   128
#define K_   50
#define L_   300
#define V_   50000
#define VT   128
#define NCH  391          // ceil(V_/VT)
#define BG   32           // legacy: groups of 4 b's
#define NKC  10           // ceil(L_/32)
#define L2E  1.4426950408889634f
#define LOSC 2048.0f
#define INV_LOSC (1.0f/2048.0f)
#define PART ((size_t)NCH * B_ * K_)   // z-partials offset inside d_out scratch

#define AFR_ENT ((size_t)B_ * NKC * 4 * 64)      // 327,680 half8 entries
#define WFR_ENT ((size_t)NCH * NKC * 4 * 128)    // 2,001,920 half8 entries
#define A_BYTES (AFR_ENT * 16)
#define W_BYTES (WFR_ENT * 16)
#define WS_NEED (2 * A_BYTES + W_BYTES + 65536)

typedef _Float16 half8  __attribute__((ext_vector_type(8)));
typedef _Float16 half4v __attribute__((ext_vector_type(4)));
typedef float    f32x4  __attribute__((ext_vector_type(4)));

__device__ __forceinline__ void split4(const float4& x, _Float16* ph, _Float16* pl) {
  half4v h, l;
  h[0] = (_Float16)x.x; h[1] = (_Float16)x.y; h[2] = (_Float16)x.z; h[3] = (_Float16)x.w;
  l[0] = (_Float16)((x.x - (float)h[0]) * LOSC);
  l[1] = (_Float16)((x.y - (float)h[1]) * LOSC);
  l[2] = (_Float16)((x.z - (float)h[2]) * LOSC);
  l[3] = (_Float16)((x.w - (float)h[3]) * LOSC);
  *(half4v*)ph = h;
  *(half4v*)pl = l;
}

__device__ __forceinline__ void cvt4(const float4& x, _Float16* ph) {
  half4v h;
  h[0] = (_Float16)x.x; h[1] = (_Float16)x.y; h[2] = (_Float16)x.z; h[3] = (_Float16)x.w;
  *(half4v*)ph = h;
}

// ---------------- precompute: A -> hi/lo fragments ----------------
__global__ void pre_a(const float* __restrict__ alpha,
                      half8* __restrict__ Ah, half8* __restrict__ Al)
{
  int t = blockIdx.x * 256 + threadIdx.x;     // < AFR_ENT
  int row = t & 63;
  int g   = (t >> 6) & 3;
  int q   = t >> 8;
  int kc  = q % NKC, b = q / NKC;
  half8 h = {}, l = {};
  if (row < K_) {
    int l0 = kc * 32 + g * 8;
    #pragma unroll
    for (int j = 0; j < 8; ++j) {
      int lc = l0 + j;
      float x = (lc < L_) ? alpha[((size_t)b * K_ + row) * L_ + lc] : 0.f;
      _Float16 hh = (_Float16)x;
      h[j] = hh;
      l[j] = (_Float16)((x - (float)hh) * LOSC);
    }
  }
  Ah[t] = h; Al[t] = l;
}

// ---------------- precompute: W -> f16 fragments (LDS-staged, coalesced) ------
__global__ __launch_bounds__(256)
void pre_w(const float* __restrict__ Wm, half8* __restrict__ Wh)
{
  __shared__ float sP[32][304];
  int t = threadIdx.x;
  int v0 = blockIdx.x * 32;                   // panel of 32 v's, within one ch
  #pragma unroll
  for (int i = 0; i < 10; ++i) {
    int idx = i * 256 + t;
    if (idx < 2400) {                          // 32 rows x 75 float4
      int r = idx / 75, qd = idx % 75;
      int v = v0 + r;
      float4 x = make_float4(0.f, 0.f, 0.f, 0.f);
      if (v < V_) x = *(const float4*)&Wm[(size_t)v * L_ + qd * 4];
      *(float4*)&sP[r][qd * 4] = x;
    }
  }
  if (t < 128) sP[t >> 2][300 + (t & 3)] = 0.f;   // pad cols 300..303
  __syncthreads();
  int ch = v0 >> 7, r0 = v0 & 127;
  #pragma unroll
  for (int i = 0; i < 5; ++i) {
    int e = i * 256 + t;                       // < 1280
    int row = e & 31, g = (e >> 5) & 3, kc = e >> 7;
    int l0 = kc * 32 + g * 8;
    half8 h = {};
    if (l0 <= 296) {
      #pragma unroll
      for (int j = 0; j < 8; ++j) h[j] = (_Float16)sP[row][l0 + j];
    }
    Wh[(((size_t)ch * NKC + kc) * 4 + g) * 128 + r0 + row] = h;
  }
}

// ---------------- fast GEMM: no LDS staging, no loop barriers ----------------
// PASS 1: hi-only (16 MFMA/kc, 8 loads/kc) -> per-chunk (m, Z) partials.
// PASS 2: 2-product (32 MFMA/kc, 12 loads/kc) -> final output.
template<int PASS>
__global__ __launch_bounds__(256, 2)
void detm_gemm_fast(const half8* __restrict__ Ah, const half8* __restrict__ Al,
                    const half8* __restrict__ Wh, float* __restrict__ out,
                    const float* __restrict__ cons)
{
  constexpr bool LO = (PASS == 2);   // include the loA*hiW product?

  __shared__ float redM[4][64];
  __shared__ float redZ[4][64];
  __shared__ float sM[128], sW[128];

  const int tid  = threadIdx.x;
  const int bid  = blockIdx.x;
  const int ch   = bid >> 6;        // 64 consecutive blocks share a W chunk
  const int bg   = bid & 63;
  const int vb   = ch * VT;
  const int wid  = tid >> 6;
  const int lane = tid & 63;
  const int slot = wid >> 1;
  const int hf   = wid & 1;
  const int g    = lane >> 4;
  const int c    = lane & 15;
  const int b    = bg * 2 + slot;

  if (PASS == 2) {
    if (tid < 128) {
      int s = tid >> 6, row = tid & 63;
      sM[tid] = cons[((bg * 2 + s) * 64 + row) * 2];
      sW[tid] = cons[((bg * 2 + s) * 64 + row) * 2 + 1];
    }
    __syncthreads();
  }

  const half8* Abase = Ah + (size_t)b * (NKC * 256) + g * 64 + c;
  const half8* Lbase = Al + (size_t)b * (NKC * 256) + g * 64 + c;
  const half8* Wbase = Wh + (size_t)ch * (NKC * 512) + g * 128 + hf * 64 + c;

  f32x4 accM[4][4] = {};   // hiA*hiW
  f32x4 accC[4][4] = {};   // loA*hiW (x2048) -- DCE'd when PASS==1
  half8 a0[4], e0[4], w0[4], a1[4], e1[4], w1[4];

  auto LOADK = [&](int kc, half8* A_, half8* E_, half8* W_) {
    #pragma unroll
    for (int mt = 0; mt < 4; ++mt) {
      A_[mt] = Abase[kc * 256 + mt * 16];
      if (LO) E_[mt] = Lbase[kc * 256 + mt * 16];
    }
    #pragma unroll
    for (int nt = 0; nt < 4; ++nt)
      W_[nt] = Wbase[kc * 512 + nt * 16];
  };
  auto MF = [&](half8* A_, half8* E_, half8* W_) {
    #pragma unroll
    for (int nt = 0; nt < 4; ++nt)
      #pragma unroll
      for (int mt = 0; mt < 4; ++mt) {
        accM[mt][nt] = __builtin_amdgcn_mfma_f32_16x16x32_f16(A_[mt], W_[nt], accM[mt][nt], 0, 0, 0);
        if (LO)
          accC[mt][nt] = __builtin_amdgcn_mfma_f32_16x16x32_f16(E_[mt], W_[nt], accC[mt][nt], 0, 0, 0);
      }
  };

  LOADK(0, a0, e0, w0);
  #pragma unroll
  for (int kc = 0; kc < NKC; kc += 2) {
    LOADK(kc + 1, a1, e1, w1);
    MF(a0, e0, w0);
    if (kc + 2 < NKC) LOADK(kc + 2, a0, e0, w0);
    MF(a1, e1, w1);
  }

  if (LO) {
    #pragma unroll
    for (int mt = 0; mt < 4; ++mt)
      #pragma unroll
      for (int nt = 0; nt < 4; ++nt)
        accM[mt][nt] = accM[mt][nt] + accC[mt][nt] * INV_LOSC;
  }

  // C layout: col = c, row = mt*16 + g*4 + reg
  if (PASS == 1) {
    #pragma unroll
    for (int mt = 0; mt < 4; ++mt) {
      #pragma unroll
      for (int r = 0; r < 4; ++r) {
        float m = -INFINITY;
        #pragma unroll
        for (int nt = 0; nt < 4; ++nt) {
          int vcol = vb + hf * 64 + nt * 16 + c;
          if (vcol < V_) m = fmaxf(m, accM[mt][nt][r]);
        }
        m = fmaxf(m, __shfl_xor(m, 1));
        m = fmaxf(m, __shfl_xor(m, 2));
        m = fmaxf(m, __shfl_xor(m, 4));
        m = fmaxf(m, __shfl_xor(m, 8));
        float z = 0.f;
        #pragma unroll
        for (int nt = 0; nt < 4; ++nt) {
          int vcol = vb + hf * 64 + nt * 16 + c;
          if (vcol < V_) z += exp2f((accM[mt][nt][r] - m) * L2E);
        }
        z += __shfl_xor(z, 1);
        z += __shfl_xor(z, 2);
        z += __shfl_xor(z, 4);
        z += __shfl_xor(z, 8);
        if (c == 0) {
          int row = mt * 16 + g * 4 + r;
          redM[wid][row] = m;
          redZ[wid][row] = z;
        }
      }
    }
    __syncthreads();
    if (tid < 128) {                 // combine the 2 col-half waves per b-slot
      int s = tid >> 6, row = tid & 63;
      float m0 = redM[s * 2][row], m1 = redM[s * 2 + 1][row];
      float z0 = redZ[s * 2][row], z1 = redZ[s * 2 + 1][row];
      float m = fmaxf(m0, m1);
      float z = z0 * exp2f((m0 - m) * L2E) + z1 * exp2f((m1 - m) * L2E);
      if (row < K_) {
        size_t idx = ((size_t)ch * B_ + (bg * 2 + s)) * K_ + row;
        out[idx] = m;
        out[PART + idx] = z;
      }
    }
  } else {
    #pragma unroll
    for (int nt = 0; nt < 4; ++nt) {
      int vcol = vb + hf * 64 + nt * 16 + c;
      float t = 0.f;
      #pragma unroll
      for (int mt = 0; mt < 4; ++mt)
        #pragma unroll
        for (int r = 0; r < 4; ++r) {
          int row = slot * 64 + mt * 16 + g * 4 + r;
          t += sW[row] * exp2f((accM[mt][nt][r] - sM[row]) * L2E);
        }
      t += __shfl_xor(t, 16);
      t += __shfl_xor(t, 32);
      if (g == 0 && vcol < V_)
        out[(size_t)b * V_ + vcol] = t;
    }
  }
}

// ---------------- legacy (R2) kernel: used when ws_size < WS_NEED -------------
template<int PASS>
__global__ __launch_bounds__(512, 2)
void detm_gemm_legacy(const float* __restrict__ alpha,
                      const float* __restrict__ Wm,
                      float* __restrict__ out,
                      const float* __restrict__ cons)
{
  __shared__ _Float16 lAh[256][40];
  __shared__ _Float16 lAl[256][40];
  __shared__ _Float16 lWh[128][40];
  __shared__ float redM[8][64];
  __shared__ float redZ[8][64];

  const int tid  = threadIdx.x;
  const int bid  = blockIdx.x;
  const int ch   = bid / BG;
  const int bg   = bid % BG;
  const int vb   = ch * VT;
  const int wid  = tid >> 6;
  const int lane = tid & 63;
  const int g    = lane >> 4;
  const int c    = lane & 15;
  const int slot = wid >> 1;
  const int hf   = wid & 1;

  if (PASS == 2 && tid < 256) {
    int s = tid >> 6, row = tid & 63;
    int b = bg * 4 + s;
    ((float*)redM)[tid] = cons[(b * 64 + row) * 2];
    ((float*)redZ)[tid] = cons[(b * 64 + row) * 2 + 1];
  }

  float4 pf[6];
  auto issue = [&](int kc) {
    #pragma unroll
    for (int i = 0; i < 4; ++i) {
      int idx = i * 512 + tid;
      int arow = idx >> 3, q = idx & 7;
      int bslot = arow >> 6, brow = arow & 63;
      int col = kc * 32 + q * 4;
      float4 x = make_float4(0.f, 0.f, 0.f, 0.f);
      if (brow < K_ && col < L_)
        x = *(const float4*)&alpha[(((size_t)(bg * 4 + bslot)) * K_ + brow) * L_ + col];
      pf[i] = x;
    }
    #pragma unroll
    for (int i = 0; i < 2; ++i) {
      int idx = i * 512 + tid;
      int wrow = idx >> 3, q = idx & 7;
      int col = kc * 32 + q * 4;
      int v = vb + wrow;
      float4 x = make_float4(0.f, 0.f, 0.f, 0.f);
      if (v < V_ && col < L_)
        x = *(const float4*)&Wm[(size_t)v * L_ + col];
      pf[4 + i] = x;
    }
  };

  f32x4 accM[4][4] = {};
  f32x4 accC[4][4] = {};

  issue(0);
  for (int kc = 0; kc < NKC; ++kc) {
    if (kc) __syncthreads();
    #pragma unroll
    for (int i = 0; i < 4; ++i) {
      int idx = i * 512 + tid;
      int arow = idx >> 3, q = idx & 7;
      split4(pf[i], &lAh[arow][q * 4], &lAl[arow][q * 4]);
    }
    #pragma unroll
    for (int i = 0; i < 2; ++i) {
      int idx = i * 512 + tid;
      int wrow = idx >> 3, q = idx & 7;
      cvt4(pf[4 + i], &lWh[wrow][q * 4]);
    }
    __syncthreads();
    if (kc + 1 < NKC) issue(kc + 1);

    half8 ah[4], al[4];
    #pragma unroll
    for (int mt = 0; mt < 4; ++mt) {
      int row = slot * 64 + mt * 16 + c;
      ah[mt] = *(const half8*)&lAh[row][g * 8];
      al[mt] = *(const half8*)&lAl[row][g * 8];
    }
    #pragma unroll
    for (int nt = 0; nt < 4; ++nt) {
      int wrow = hf * 64 + nt * 16 + c;
      half8 bh = *(const half8*)&lWh[wrow][g * 8];
      #pragma unroll
      for (int mt = 0; mt < 4; ++mt) {
        accM[mt][nt] = __builtin_amdgcn_mfma_f32_16x16x32_f16(ah[mt], bh, accM[mt][nt], 0, 0, 0);
        accC[mt][nt] = __builtin_amdgcn_mfma_f32_16x16x32_f16(al[mt], bh, accC[mt][nt], 0, 0, 0);
      }
    }
  }

  #pragma unroll
  for (int mt = 0; mt < 4; ++mt)
    #pragma unroll
    for (int nt = 0; nt < 4; ++nt)
      accM[mt][nt] = accM[mt][nt] + accC[mt][nt] * INV_LOSC;

  if (PASS == 1) {
    #pragma unroll
    for (int mt = 0; mt < 4; ++mt) {
      #pragma unroll
      for (int r = 0; r < 4; ++r) {
        float m = -INFINITY;
        #pragma unroll
        for (int nt = 0; nt < 4; ++nt) {
          int vcol = vb + hf * 64 + nt * 16 + c;
          if (vcol < V_) m = fmaxf(m, accM[mt][nt][r]);
        }
        m = fmaxf(m, __shfl_xor(m, 1));
        m = fmaxf(m, __shfl_xor(m, 2));
        m = fmaxf(m, __shfl_xor(m, 4));
        m = fmaxf(m, __shfl_xor(m, 8));
        float z = 0.f;
        #pragma unroll
        for (int nt = 0; nt < 4; ++nt) {
          int vcol = vb + hf * 64 + nt * 16 + c;
          if (vcol < V_) z += exp2f((accM[mt][nt][r] - m) * L2E);
        }
        z += __shfl_xor(z, 1);
        z += __shfl_xor(z, 2);
        z += __shfl_xor(z, 4);
        z += __shfl_xor(z, 8);
        if (c == 0) {
          int row = mt * 16 + g * 4 + r;
          redM[wid][row] = m;
          redZ[wid][row] = z;
        }
      }
    }
    __syncthreads();
    if (tid < 256) {
      int s = tid >> 6, row = tid & 63;
      float m0 = redM[s * 2][row],  m1 = redM[s * 2 + 1][row];
      float z0 = redZ[s * 2][row],  z1 = redZ[s * 2 + 1][row];
      float m = fmaxf(m0, m1);
      float z = z0 * exp2f((m0 - m) * L2E) + z1 * exp2f((m1 - m) * L2E);
      if (row < K_) {
        int b = bg * 4 + s;
        size_t idx = ((size_t)ch * B_ + b) * K_ + row;
        out[idx] = m;
        out[PART + idx] = z;
      }
    }
  } else {
    const float* sM = (const float*)redM;
    const float* sW = (const float*)redZ;
    #pragma unroll
    for (int nt = 0; nt < 4; ++nt) {
      int vcol = vb + hf * 64 + nt * 16 + c;
      float t = 0.f;
      #pragma unroll
      for (int mt = 0; mt < 4; ++mt)
        #pragma unroll
        for (int r = 0; r < 4; ++r) {
          int row = slot * 64 + mt * 16 + g * 4 + r;
          t += sW[row] * exp2f((accM[mt][nt][r] - sM[row]) * L2E);
        }
      t += __shfl_xor(t, 16);
      t += __shfl_xor(t, 32);
      if (g == 0 && vcol < V_)
        out[(size_t)(bg * 4 + slot) * V_ + vcol] = t;
    }
  }
}

// Reduce per-chunk partials -> per-row (m_k, theta_k/Z_k).
__global__ void detm_mid(const float* __restrict__ theta,
                         const float* __restrict__ pbuf,
                         float* __restrict__ cons)
{
  __shared__ float sm[4][64], sz[4][64];
  int b = blockIdx.x, t = threadIdx.x;
  int k = t & 63, seg = t >> 6;
  float mx = -INFINITY, z = 0.f;
  if (k < K_) {
    for (int ch = seg; ch < NCH; ch += 4) {
      size_t idx = ((size_t)ch * B_ + b) * K_ + k;
      float m = pbuf[idx];
      float zz = pbuf[PART + idx];
      float nm = fmaxf(mx, m);
      z = z * exp2f((mx - nm) * L2E) + zz * exp2f((m - nm) * L2E);
      mx = nm;
    }
  }
  sm[seg][k] = mx; sz[seg][k] = z;
  __syncthreads();
  if (seg == 0) {
    float m = sm[0][k];
    #pragma unroll
    for (int s = 1; s < 4; ++s) m = fmaxf(m, sm[s][k]);
    float zt = 0.f;
    #pragma unroll
    for (int s = 0; s < 4; ++s) zt += sz[s][k] * exp2f((sm[s][k] - m) * L2E);
    float mm = 0.f, wgt = 0.f;
    if (k < K_) { mm = m; wgt = theta[b * K_ + k] / zt; }
    cons[(b * 64 + k) * 2]     = mm;
    cons[(b * 64 + k) * 2 + 1] = wgt;
  }
}

extern "C" void kernel_launch(void* const* d_in, const int* in_sizes, int n_in,
                              void* d_out, int out_size, void* d_ws, size_t ws_size,
                              hipStream_t stream) {
  const float* theta = (const float*)d_in[0];
  const float* alpha = (const float*)d_in[1];
  const float* Wm    = (const float*)d_in[2];
  float* out = (float*)d_out;

  if (ws_size >= WS_NEED) {
    half8* Ah = (half8*)d_ws;
    half8* Al = Ah + AFR_ENT;
    half8* Wh = Al + AFR_ENT;
    float* cons = (float*)((char*)d_ws + 2 * A_BYTES + W_BYTES);

    pre_a<<<dim3((int)(AFR_ENT / 256)), dim3(256), 0, stream>>>(alpha, Ah, Al);
    pre_w<<<dim3((V_ + 47 + 32 - 1) / 32), dim3(256), 0, stream>>>(Wm, Wh);  // 1564 panels
    detm_gemm_fast<1><<<dim3(NCH * 64), dim3(256), 0, stream>>>(Ah, Al, Wh, out, cons);
    detm_mid<<<dim3(B_), dim3(256), 0, stream>>>(theta, out, cons);
    detm_gemm_fast<2><<<dim3(NCH * 64), dim3(256), 0, stream>>>(Ah, Al, Wh, out, cons);
  } else {
    float* cons = (float*)d_ws;   // 64 KB
    detm_gemm_legacy<1><<<dim3(NCH * BG), dim3(512), 0, stream>>>(alpha, Wm, out, cons);
    detm_mid<<<dim3(B_), dim3(256), 0, stream>>>(theta, out, cons);
    detm_gemm_legacy<2><<<dim3(NCH * BG), dim3(512), 0, stream>>>(alpha, Wm, out, cons);
  }
}

// Round 14
// 949.827 us; speedup vs baseline: 4.6944x; 1.1891x over previous
//
#include <hip/hip_runtime.h>

// word_dist[b,v] = sum_k theta[b,k] * softmax_v(alpha[b,k,:] . W[v,:])
// B=128, K=50, L=300, V=50000, f32 in/out.
//
// R14: both passes HI-ONLY f16 (identical perturbed logits in pass1 & pass2 ->
// Z-mismatch cancels; output = exact softmax of s~, sigma~7e-3 -> ~5e-4 absmax).
// No Al buffer at all. 16 MFMA/kc, 8 loads/kc, ~150 regs, launch_bounds(256,3)
// for 3 waves/SIMD latency hiding. Falls back to R2 kernel if ws too small.

#define B_   128
#define K_   50
#define L_   300
#define V_   50000
#define VT   128
#define NCH  391          // ceil(V_/VT)
#define BG   32           // legacy: groups of 4 b's
#define NKC  10           // ceil(L_/32)
#define L2E  1.4426950408889634f
#define LOSC 2048.0f
#define INV_LOSC (1.0f/2048.0f)
#define PART ((size_t)NCH * B_ * K_)   // z-partials offset inside d_out scratch

#define AFR_ENT ((size_t)B_ * NKC * 4 * 64)      // 327,680 half8 entries
#define WFR_ENT ((size_t)NCH * NKC * 4 * 128)    // 2,001,920 half8 entries
#define A_BYTES (AFR_ENT * 16)
#define W_BYTES (WFR_ENT * 16)
#define WS_NEED (A_BYTES + W_BYTES + 65536)

typedef _Float16 half8  __attribute__((ext_vector_type(8)));
typedef _Float16 half4v __attribute__((ext_vector_type(4)));
typedef float    f32x4  __attribute__((ext_vector_type(4)));

__device__ __forceinline__ void split4(const float4& x, _Float16* ph, _Float16* pl) {
  half4v h, l;
  h[0] = (_Float16)x.x; h[1] = (_Float16)x.y; h[2] = (_Float16)x.z; h[3] = (_Float16)x.w;
  l[0] = (_Float16)((x.x - (float)h[0]) * LOSC);
  l[1] = (_Float16)((x.y - (float)h[1]) * LOSC);
  l[2] = (_Float16)((x.z - (float)h[2]) * LOSC);
  l[3] = (_Float16)((x.w - (float)h[3]) * LOSC);
  *(half4v*)ph = h;
  *(half4v*)pl = l;
}

__device__ __forceinline__ void cvt4(const float4& x, _Float16* ph) {
  half4v h;
  h[0] = (_Float16)x.x; h[1] = (_Float16)x.y; h[2] = (_Float16)x.z; h[3] = (_Float16)x.w;
  *(half4v*)ph = h;
}

// ---------------- precompute: A -> f16 hi fragments only ----------------
__global__ void pre_a(const float* __restrict__ alpha, half8* __restrict__ Ah)
{
  int t = blockIdx.x * 256 + threadIdx.x;     // < AFR_ENT
  int row = t & 63;
  int g   = (t >> 6) & 3;
  int q   = t >> 8;
  int kc  = q % NKC, b = q / NKC;
  half8 h = {};
  if (row < K_) {
    int l0 = kc * 32 + g * 8;
    #pragma unroll
    for (int j = 0; j < 8; ++j) {
      int lc = l0 + j;
      float x = (lc < L_) ? alpha[((size_t)b * K_ + row) * L_ + lc] : 0.f;
      h[j] = (_Float16)x;
    }
  }
  Ah[t] = h;
}

// ---------------- precompute: W -> f16 fragments (LDS-staged, coalesced) ------
__global__ __launch_bounds__(256)
void pre_w(const float* __restrict__ Wm, half8* __restrict__ Wh)
{
  __shared__ float sP[32][304];
  int t = threadIdx.x;
  int v0 = blockIdx.x * 32;                   // panel of 32 v's, within one ch
  #pragma unroll
  for (int i = 0; i < 10; ++i) {
    int idx = i * 256 + t;
    if (idx < 2400) {                          // 32 rows x 75 float4
      int r = idx / 75, qd = idx % 75;
      int v = v0 + r;
      float4 x = make_float4(0.f, 0.f, 0.f, 0.f);
      if (v < V_) x = *(const float4*)&Wm[(size_t)v * L_ + qd * 4];
      *(float4*)&sP[r][qd * 4] = x;
    }
  }
  if (t < 128) sP[t >> 2][300 + (t & 3)] = 0.f;   // pad cols 300..303
  __syncthreads();
  int ch = v0 >> 7, r0 = v0 & 127;
  #pragma unroll
  for (int i = 0; i < 5; ++i) {
    int e = i * 256 + t;                       // < 1280
    int row = e & 31, g = (e >> 5) & 3, kc = e >> 7;
    int l0 = kc * 32 + g * 8;
    half8 h = {};
    if (l0 <= 296) {
      #pragma unroll
      for (int j = 0; j < 8; ++j) h[j] = (_Float16)sP[row][l0 + j];
    }
    Wh[(((size_t)ch * NKC + kc) * 4 + g) * 128 + r0 + row] = h;
  }
}

// ---------------- fast GEMM: hi-only, no LDS staging, no loop barriers --------
// Both passes: 16 MFMA/kc, 8 b128 loads/kc, ping-pong double-buffered.
template<int PASS>
__global__ __launch_bounds__(256, 3)
void detm_gemm_fast(const half8* __restrict__ Ah,
                    const half8* __restrict__ Wh, float* __restrict__ out,
                    const float* __restrict__ cons)
{
  __shared__ float redM[4][64];
  __shared__ float redZ[4][64];
  __shared__ float sM[128], sW[128];

  const int tid  = threadIdx.x;
  const int bid  = blockIdx.x;
  const int ch   = bid >> 6;        // 64 consecutive blocks share a W chunk
  const int bg   = bid & 63;
  const int vb   = ch * VT;
  const int wid  = tid >> 6;
  const int lane = tid & 63;
  const int slot = wid >> 1;
  const int hf   = wid & 1;
  const int g    = lane >> 4;
  const int c    = lane & 15;
  const int b    = bg * 2 + slot;

  if (PASS == 2) {
    if (tid < 128) {
      int s = tid >> 6, row = tid & 63;
      sM[tid] = cons[((bg * 2 + s) * 64 + row) * 2];
      sW[tid] = cons[((bg * 2 + s) * 64 + row) * 2 + 1];
    }
    __syncthreads();
  }

  const half8* Abase = Ah + (size_t)b * (NKC * 256) + g * 64 + c;
  const half8* Wbase = Wh + (size_t)ch * (NKC * 512) + g * 128 + hf * 64 + c;

  f32x4 accM[4][4] = {};   // hiA*hiW
  half8 a0[4], w0[4], a1[4], w1[4];

  auto LOADK = [&](int kc, half8* A_, half8* W_) {
    #pragma unroll
    for (int mt = 0; mt < 4; ++mt)
      A_[mt] = Abase[kc * 256 + mt * 16];
    #pragma unroll
    for (int nt = 0; nt < 4; ++nt)
      W_[nt] = Wbase[kc * 512 + nt * 16];
  };
  auto MF = [&](half8* A_, half8* W_) {
    #pragma unroll
    for (int nt = 0; nt < 4; ++nt)
      #pragma unroll
      for (int mt = 0; mt < 4; ++mt)
        accM[mt][nt] = __builtin_amdgcn_mfma_f32_16x16x32_f16(A_[mt], W_[nt], accM[mt][nt], 0, 0, 0);
  };

  LOADK(0, a0, w0);
  #pragma unroll
  for (int kc = 0; kc < NKC; kc += 2) {
    LOADK(kc + 1, a1, w1);
    MF(a0, w0);
    if (kc + 2 < NKC) LOADK(kc + 2, a0, w0);
    MF(a1, w1);
  }

  // C layout: col = c, row = mt*16 + g*4 + reg
  if (PASS == 1) {
    #pragma unroll
    for (int mt = 0; mt < 4; ++mt) {
      #pragma unroll
      for (int r = 0; r < 4; ++r) {
        float m = -INFINITY;
        #pragma unroll
        for (int nt = 0; nt < 4; ++nt) {
          int vcol = vb + hf * 64 + nt * 16 + c;
          if (vcol < V_) m = fmaxf(m, accM[mt][nt][r]);
        }
        m = fmaxf(m, __shfl_xor(m, 1));
        m = fmaxf(m, __shfl_xor(m, 2));
        m = fmaxf(m, __shfl_xor(m, 4));
        m = fmaxf(m, __shfl_xor(m, 8));
        float z = 0.f;
        #pragma unroll
        for (int nt = 0; nt < 4; ++nt) {
          int vcol = vb + hf * 64 + nt * 16 + c;
          if (vcol < V_) z += exp2f((accM[mt][nt][r] - m) * L2E);
        }
        z += __shfl_xor(z, 1);
        z += __shfl_xor(z, 2);
        z += __shfl_xor(z, 4);
        z += __shfl_xor(z, 8);
        if (c == 0) {
          int row = mt * 16 + g * 4 + r;
          redM[wid][row] = m;
          redZ[wid][row] = z;
        }
      }
    }
    __syncthreads();
    if (tid < 128) {                 // combine the 2 col-half waves per b-slot
      int s = tid >> 6, row = tid & 63;
      float m0 = redM[s * 2][row], m1 = redM[s * 2 + 1][row];
      float z0 = redZ[s * 2][row], z1 = redZ[s * 2 + 1][row];
      float m = fmaxf(m0, m1);
      float z = z0 * exp2f((m0 - m) * L2E) + z1 * exp2f((m1 - m) * L2E);
      if (row < K_) {
        size_t idx = ((size_t)ch * B_ + (bg * 2 + s)) * K_ + row;
        out[idx] = m;
        out[PART + idx] = z;
      }
    }
  } else {
    #pragma unroll
    for (int nt = 0; nt < 4; ++nt) {
      int vcol = vb + hf * 64 + nt * 16 + c;
      float t = 0.f;
      #pragma unroll
      for (int mt = 0; mt < 4; ++mt)
        #pragma unroll
        for (int r = 0; r < 4; ++r) {
          int row = slot * 64 + mt * 16 + g * 4 + r;
          t += sW[row] * exp2f((accM[mt][nt][r] - sM[row]) * L2E);
        }
      t += __shfl_xor(t, 16);
      t += __shfl_xor(t, 32);
      if (g == 0 && vcol < V_)
        out[(size_t)b * V_ + vcol] = t;
    }
  }
}

// ---------------- legacy (R2) kernel: used when ws_size < WS_NEED -------------
template<int PASS>
__global__ __launch_bounds__(512, 2)
void detm_gemm_legacy(const float* __restrict__ alpha,
                      const float* __restrict__ Wm,
                      float* __restrict__ out,
                      const float* __restrict__ cons)
{
  __shared__ _Float16 lAh[256][40];
  __shared__ _Float16 lAl[256][40];
  __shared__ _Float16 lWh[128][40];
  __shared__ float redM[8][64];
  __shared__ float redZ[8][64];

  const int tid  = threadIdx.x;
  const int bid  = blockIdx.x;
  const int ch   = bid / BG;
  const int bg   = bid % BG;
  const int vb   = ch * VT;
  const int wid  = tid >> 6;
  const int lane = tid & 63;
  const int g    = lane >> 4;
  const int c    = lane & 15;
  const int slot = wid >> 1;
  const int hf   = wid & 1;

  if (PASS == 2 && tid < 256) {
    int s = tid >> 6, row = tid & 63;
    int b = bg * 4 + s;
    ((float*)redM)[tid] = cons[(b * 64 + row) * 2];
    ((float*)redZ)[tid] = cons[(b * 64 + row) * 2 + 1];
  }

  float4 pf[6];
  auto issue = [&](int kc) {
    #pragma unroll
    for (int i = 0; i < 4; ++i) {
      int idx = i * 512 + tid;
      int arow = idx >> 3, q = idx & 7;
      int bslot = arow >> 6, brow = arow & 63;
      int col = kc * 32 + q * 4;
      float4 x = make_float4(0.f, 0.f, 0.f, 0.f);
      if (brow < K_ && col < L_)
        x = *(const float4*)&alpha[(((size_t)(bg * 4 + bslot)) * K_ + brow) * L_ + col];
      pf[i] = x;
    }
    #pragma unroll
    for (int i = 0; i < 2; ++i) {
      int idx = i * 512 + tid;
      int wrow = idx >> 3, q = idx & 7;
      int col = kc * 32 + q * 4;
      int v = vb + wrow;
      float4 x = make_float4(0.f, 0.f, 0.f, 0.f);
      if (v < V_ && col < L_)
        x = *(const float4*)&Wm[(size_t)v * L_ + col];
      pf[4 + i] = x;
    }
  };

  f32x4 accM[4][4] = {};
  f32x4 accC[4][4] = {};

  issue(0);
  for (int kc = 0; kc < NKC; ++kc) {
    if (kc) __syncthreads();
    #pragma unroll
    for (int i = 0; i < 4; ++i) {
      int idx = i * 512 + tid;
      int arow = idx >> 3, q = idx & 7;
      split4(pf[i], &lAh[arow][q * 4], &lAl[arow][q * 4]);
    }
    #pragma unroll
    for (int i = 0; i < 2; ++i) {
      int idx = i * 512 + tid;
      int wrow = idx >> 3, q = idx & 7;
      cvt4(pf[4 + i], &lWh[wrow][q * 4]);
    }
    __syncthreads();
    if (kc + 1 < NKC) issue(kc + 1);

    half8 ah[4], al[4];
    #pragma unroll
    for (int mt = 0; mt < 4; ++mt) {
      int row = slot * 64 + mt * 16 + c;
      ah[mt] = *(const half8*)&lAh[row][g * 8];
      al[mt] = *(const half8*)&lAl[row][g * 8];
    }
    #pragma unroll
    for (int nt = 0; nt < 4; ++nt) {
      int wrow = hf * 64 + nt * 16 + c;
      half8 bh = *(const half8*)&lWh[wrow][g * 8];
      #pragma unroll
      for (int mt = 0; mt < 4; ++mt) {
        accM[mt][nt] = __builtin_amdgcn_mfma_f32_16x16x32_f16(ah[mt], bh, accM[mt][nt], 0, 0, 0);
        accC[mt][nt] = __builtin_amdgcn_mfma_f32_16x16x32_f16(al[mt], bh, accC[mt][nt], 0, 0, 0);
      }
    }
  }

  #pragma unroll
  for (int mt = 0; mt < 4; ++mt)
    #pragma unroll
    for (int nt = 0; nt < 4; ++nt)
      accM[mt][nt] = accM[mt][nt] + accC[mt][nt] * INV_LOSC;

  if (PASS == 1) {
    #pragma unroll
    for (int mt = 0; mt < 4; ++mt) {
      #pragma unroll
      for (int r = 0; r < 4; ++r) {
        float m = -INFINITY;
        #pragma unroll
        for (int nt = 0; nt < 4; ++nt) {
          int vcol = vb + hf * 64 + nt * 16 + c;
          if (vcol < V_) m = fmaxf(m, accM[mt][nt][r]);
        }
        m = fmaxf(m, __shfl_xor(m, 1));
        m = fmaxf(m, __shfl_xor(m, 2));
        m = fmaxf(m, __shfl_xor(m, 4));
        m = fmaxf(m, __shfl_xor(m, 8));
        float z = 0.f;
        #pragma unroll
        for (int nt = 0; nt < 4; ++nt) {
          int vcol = vb + hf * 64 + nt * 16 + c;
          if (vcol < V_) z += exp2f((accM[mt][nt][r] - m) * L2E);
        }
        z += __shfl_xor(z, 1);
        z += __shfl_xor(z, 2);
        z += __shfl_xor(z, 4);
        z += __shfl_xor(z, 8);
        if (c == 0) {
          int row = mt * 16 + g * 4 + r;
          redM[wid][row] = m;
          redZ[wid][row] = z;
        }
      }
    }
    __syncthreads();
    if (tid < 256) {
      int s = tid >> 6, row = tid & 63;
      float m0 = redM[s * 2][row],  m1 = redM[s * 2 + 1][row];
      float z0 = redZ[s * 2][row],  z1 = redZ[s * 2 + 1][row];
      float m = fmaxf(m0, m1);
      float z = z0 * exp2f((m0 - m) * L2E) + z1 * exp2f((m1 - m) * L2E);
      if (row < K_) {
        int b = bg * 4 + s;
        size_t idx = ((size_t)ch * B_ + b) * K_ + row;
        out[idx] = m;
        out[PART + idx] = z;
      }
    }
  } else {
    const float* sM = (const float*)redM;
    const float* sW = (const float*)redZ;
    #pragma unroll
    for (int nt = 0; nt < 4; ++nt) {
      int vcol = vb + hf * 64 + nt * 16 + c;
      float t = 0.f;
      #pragma unroll
      for (int mt = 0; mt < 4; ++mt)
        #pragma unroll
        for (int r = 0; r < 4; ++r) {
          int row = slot * 64 + mt * 16 + g * 4 + r;
          t += sW[row] * exp2f((accM[mt][nt][r] - sM[row]) * L2E);
        }
      t += __shfl_xor(t, 16);
      t += __shfl_xor(t, 32);
      if (g == 0 && vcol < V_)
        out[(size_t)(bg * 4 + slot) * V_ + vcol] = t;
    }
  }
}

// Reduce per-chunk partials -> per-row (m_k, theta_k/Z_k).
__global__ void detm_mid(const float* __restrict__ theta,
                         const float* __restrict__ pbuf,
                         float* __restrict__ cons)
{
  __shared__ float sm[4][64], sz[4][64];
  int b = blockIdx.x, t = threadIdx.x;
  int k = t & 63, seg = t >> 6;
  float mx = -INFINITY, z = 0.f;
  if (k < K_) {
    for (int ch = seg; ch < NCH; ch += 4) {
      size_t idx = ((size_t)ch * B_ + b) * K_ + k;
      float m = pbuf[idx];
      float zz = pbuf[PART + idx];
      float nm = fmaxf(mx, m);
      z = z * exp2f((mx - nm) * L2E) + zz * exp2f((m - nm) * L2E);
      mx = nm;
    }
  }
  sm[seg][k] = mx; sz[seg][k] = z;
  __syncthreads();
  if (seg == 0) {
    float m = sm[0][k];
    #pragma unroll
    for (int s = 1; s < 4; ++s) m = fmaxf(m, sm[s][k]);
    float zt = 0.f;
    #pragma unroll
    for (int s = 0; s < 4; ++s) zt += sz[s][k] * exp2f((sm[s][k] - m) * L2E);
    float mm = 0.f, wgt = 0.f;
    if (k < K_) { mm = m; wgt = theta[b * K_ + k] / zt; }
    cons[(b * 64 + k) * 2]     = mm;
    cons[(b * 64 + k) * 2 + 1] = wgt;
  }
}

extern "C" void kernel_launch(void* const* d_in, const int* in_sizes, int n_in,
                              void* d_out, int out_size, void* d_ws, size_t ws_size,
                              hipStream_t stream) {
  const float* theta = (const float*)d_in[0];
  const float* alpha = (const float*)d_in[1];
  const float* Wm    = (const float*)d_in[2];
  float* out = (float*)d_out;

  if (ws_size >= WS_NEED) {
    half8* Ah = (half8*)d_ws;
    half8* Wh = Ah + AFR_ENT;
    float* cons = (float*)((char*)d_ws + A_BYTES + W_BYTES);

    pre_a<<<dim3((int)(AFR_ENT / 256)), dim3(256), 0, stream>>>(alpha, Ah);
    pre_w<<<dim3((V_ + 47 + 32 - 1) / 32), dim3(256), 0, stream>>>(Wm, Wh);  // 1564 panels
    detm_gemm_fast<1><<<dim3(NCH * 64), dim3(256), 0, stream>>>(Ah, Wh, out, cons);
    detm_mid<<<dim3(B_), dim3(256), 0, stream>>>(theta, out, cons);
    detm_gemm_fast<2><<<dim3(NCH * 64), dim3(256), 0, stream>>>(Ah, Wh, out, cons);
  } else {
    float* cons = (float*)d_ws;   // 64 KB
    detm_gemm_legacy<1><<<dim3(NCH * BG), dim3(512), 0, stream>>>(alpha, Wm, out, cons);
    detm_mid<<<dim3(B_), dim3(256), 0, stream>>>(theta, out, cons);
    detm_gemm_legacy<2><<<dim3(NCH * BG), dim3(512), 0, stream>>>(alpha, Wm, out, cons);
  }
}